// Round 7
// baseline (1186.866 us; speedup 1.0000x reference)
//
#include <hip/hip_runtime.h>
#include <stdint.h>

#define NN 50000
#define EE 800000
#define DH 128
#define NC 40
#define KCAT (14*DH)   // 1792
#define CAP 64         // ELL capacity; deg ~ Binom(800k,1/50k), P(deg>64) ~ 1e-18
#define LPA 136        // LDS row pad (shorts): 272B = 68 banks ≡ 4 mod 32 -> even bank spread

typedef __bf16 bf16x8 __attribute__((ext_vector_type(8)));
typedef float floatx4 __attribute__((ext_vector_type(4)));

__device__ __forceinline__ float bf2f(unsigned short u) {
  union { uint32_t i; float f; } v; v.i = ((uint32_t)u) << 16; return v.f;
}
__device__ __forceinline__ unsigned short f2bf(float f) {
  union { float f; uint32_t i; } v; v.f = f;
  uint32_t x = v.i;
  uint32_t r = (x + 0x7fffu + ((x >> 16) & 1u)) >> 16;  // RNE
  return (unsigned short)r;
}

// ---------------- utility ----------------
__global__ void zero_i32(int* p, int n) {
  int i = blockIdx.x * blockDim.x + threadIdx.x;
  if (i < n) p[i] = 0;
}

// Probe x's first 4096 16-bit words (R3: confirmed fp32 inputs; keep dtype-agnostic).
__global__ void detect_dtype(const unsigned short* xw, int* wildcnt) {
  int t = threadIdx.x;
  int wild = 0;
  for (int i = t; i < 4096; i += 256) {
    unsigned e = (xw[i] >> 7) & 0xFF;
    if (e >= 0x90) wild++;
  }
  if (wild) atomicAdd(wildcnt, wild);
}

__global__ void convert_f(const void* in, unsigned short* outp, int n, const int* flag) {
  bool isf32 = (*flag) > 32;
  for (int i = blockIdx.x * blockDim.x + threadIdx.x; i < n;
       i += gridDim.x * blockDim.x) {
    outp[i] = isf32 ? f2bf(((const float*)in)[i]) : ((const unsigned short*)in)[i];
  }
}

// B[L][K][M] -> BT[L][Mpad][K] (bf16 out), zero-pad n>=M
__global__ void transpose_w(const void* B, unsigned short* BT,
                            int L, int K, int M, int Mpad, const int* flag) {
  bool isf32 = (*flag) > 32;
  int total = L * Mpad * K;
  for (int idx = blockIdx.x * blockDim.x + threadIdx.x; idx < total;
       idx += gridDim.x * blockDim.x) {
    int k = idx % K;
    int n = (idx / K) % Mpad;
    int l = idx / (K * Mpad);
    unsigned short v = 0;
    if (n < M) {
      size_t si = (size_t)l * K * M + (size_t)k * M + n;
      v = isf32 ? f2bf(((const float*)B)[si]) : ((const unsigned short*)B)[si];
    }
    BT[idx] = v;
  }
}

// ---------------- ELL adjacency build ----------------
__global__ void build_ell(const int* __restrict__ src, const int* __restrict__ dst,
                          const void* __restrict__ w,
                          int* __restrict__ cnt, int2* __restrict__ ell,
                          const int* __restrict__ flag) {
  bool isf32 = (*flag) > 32;
  int e = blockIdx.x * blockDim.x + threadIdx.x;
  if (e >= EE) return;
  int d = dst[e];
  if ((unsigned)d >= NN) return;
  int p = atomicAdd(&cnt[d], 1);
  if (p >= CAP) return;
  int s = src[e];
  float wf = isf32 ? ((const float*)w)[e] : bf2f(((const unsigned short*)w)[e]);
  if ((unsigned)s >= NN) { s = 0; wf = 0.f; }
  union { float f; int i; } wv; wv.f = wf;
  ell[(size_t)d * CAP + p] = make_int2(s, wv.i);
}

// ---------------- GEMM: C[N,128] = A[N,K] @ B[K,128] (+bias) ----------------
// A contiguous rows (lda = K). BT pre-transposed [128][ldb=K]. 64-row blocks,
// single-stage LDS per 128-k chunk (one barrier pair), epilogue through LDS
// for streaming dwordx4 C-writes.
__global__ __launch_bounds__(256) void gemm_h(
    const unsigned short* __restrict__ A, int lda,
    const unsigned short* __restrict__ BT, int ldb, int K,
    unsigned short* __restrict__ C, const unsigned short* __restrict__ bias) {
  __shared__ unsigned short As[64][LPA];
  __shared__ unsigned short Bs[128][LPA];
  int t = threadIdx.x;
  int wave = t >> 6, lane = t & 63;
  int q = lane >> 4, mn = lane & 15;
  int r0 = blockIdx.x * 64;
  floatx4 acc[4][2];  // rows i*16+, cols wave*32 + j*16+
  floatx4 zf = {0.f, 0.f, 0.f, 0.f};
  #pragma unroll
  for (int i = 0; i < 4; ++i)
    #pragma unroll
    for (int j = 0; j < 2; ++j) acc[i][j] = zf;

  int arow = t >> 2;            // 0..63
  int akc = (t & 3) << 5;       // 0,32,64,96 shorts (64B per thread)
  int brow = t >> 1;            // 0..127
  int bkc = (t & 1) << 6;       // 0,64 shorts (128B per thread)

  for (int k0 = 0; k0 < K; k0 += 128) {
    {  // stage A: 64 rows x 128k, 4 threads/row x 64B contiguous
      uint4 v[4] = {};
      if (r0 + arow < NN) {
        const unsigned short* src = A + (size_t)(r0 + arow) * lda + k0 + akc;
        #pragma unroll
        for (int i = 0; i < 4; ++i) v[i] = *(const uint4*)(src + i * 8);
      }
      #pragma unroll
      for (int i = 0; i < 4; ++i) *(uint4*)(&As[arow][akc + i * 8]) = v[i];
    }
    {  // stage B: 128 rows x 128k, 2 threads/row x 128B contiguous
      const unsigned short* src = BT + (size_t)brow * ldb + k0 + bkc;
      #pragma unroll
      for (int i = 0; i < 8; ++i) {
        uint4 v = *(const uint4*)(src + i * 8);
        *(uint4*)(&Bs[brow][bkc + i * 8]) = v;
      }
    }
    __syncthreads();
    #pragma unroll
    for (int ks = 0; ks < 4; ++ks) {
      bf16x8 fa[4], fb[2];
      #pragma unroll
      for (int i = 0; i < 4; ++i)
        fa[i] = *(const bf16x8*)(&As[i * 16 + mn][ks * 32 + q * 8]);
      #pragma unroll
      for (int j = 0; j < 2; ++j)
        fb[j] = *(const bf16x8*)(&Bs[wave * 32 + j * 16 + mn][ks * 32 + q * 8]);
      #pragma unroll
      for (int i = 0; i < 4; ++i)
        #pragma unroll
        for (int j = 0; j < 2; ++j)
          acc[i][j] = __builtin_amdgcn_mfma_f32_16x16x32_bf16(fa[i], fb[j], acc[i][j], 0, 0, 0);
    }
    __syncthreads();
  }
  // epilogue: acc -> LDS (bf16) -> streaming coalesced stores
  // C/D: col = lane&15, row = (lane>>4)*4 + reg
  #pragma unroll
  for (int i = 0; i < 4; ++i) {
    #pragma unroll
    for (int j = 0; j < 2; ++j) {
      int col = wave * 32 + j * 16 + mn;
      float badd = bias ? bf2f(bias[col]) : 0.0f;
      #pragma unroll
      for (int rr = 0; rr < 4; ++rr)
        As[i * 16 + q * 4 + rr][col] = f2bf(acc[i][j][rr] + badd);
    }
  }
  __syncthreads();
  if (r0 + arow < NN) {
    unsigned short* dst = C + (size_t)(r0 + arow) * 128 + ((t & 3) << 5);
    #pragma unroll
    for (int i = 0; i < 4; ++i)
      *(uint4*)(dst + i * 8) = *(const uint4*)(&As[arow][((t & 3) << 5) + i * 8]);
  }
}

// ---------------- per-layer s15 accumulate: s15[N,40] += x_l[N,128] @ W15_blk ----------
// BT = W15T + koff (row stride ldb=KCAT). 128-row blocks own rows exclusively -> plain +=.
__global__ __launch_bounds__(256) void gemm_acc(
    const unsigned short* __restrict__ A, const unsigned short* __restrict__ BT, int ldb,
    float* __restrict__ C) {
  __shared__ unsigned short As[128][LPA];
  __shared__ unsigned short Bs[48][LPA];
  int t = threadIdx.x;
  int wave = t >> 6, lane = t & 63;
  int q = lane >> 4, mn = lane & 15;
  int r0 = blockIdx.x * 128;
  floatx4 acc[2][3];
  floatx4 zf = {0.f, 0.f, 0.f, 0.f};
  #pragma unroll
  for (int i = 0; i < 2; ++i)
    #pragma unroll
    for (int j = 0; j < 3; ++j) acc[i][j] = zf;

  {  // stage A: 128 rows x 128k, 2 threads/row x 128B
    int arow = t >> 1;
    int akc = (t & 1) << 6;
    uint4 v[8] = {};
    if (r0 + arow < NN) {
      const unsigned short* src = A + (size_t)(r0 + arow) * 128 + akc;
      #pragma unroll
      for (int i = 0; i < 8; ++i) v[i] = *(const uint4*)(src + i * 8);
    }
    #pragma unroll
    for (int i = 0; i < 8; ++i) *(uint4*)(&As[arow][akc + i * 8]) = v[i];
  }
  if (t < 192) {  // stage B: 48 rows x 128k, 4 threads/row x 64B
    int browb = t >> 2;
    int bkcb = (t & 3) << 5;
    const unsigned short* src = BT + (size_t)browb * ldb + bkcb;
    #pragma unroll
    for (int i = 0; i < 4; ++i) {
      uint4 v = *(const uint4*)(src + i * 8);
      *(uint4*)(&Bs[browb][bkcb + i * 8]) = v;
    }
  }
  __syncthreads();
  #pragma unroll
  for (int ks = 0; ks < 4; ++ks) {
    bf16x8 fa[2], fb[3];
    #pragma unroll
    for (int i = 0; i < 2; ++i)
      fa[i] = *(const bf16x8*)(&As[wave * 32 + i * 16 + mn][ks * 32 + q * 8]);
    #pragma unroll
    for (int j = 0; j < 3; ++j)
      fb[j] = *(const bf16x8*)(&Bs[j * 16 + mn][ks * 32 + q * 8]);
    #pragma unroll
    for (int i = 0; i < 2; ++i)
      #pragma unroll
      for (int j = 0; j < 3; ++j)
        acc[i][j] = __builtin_amdgcn_mfma_f32_16x16x32_bf16(fa[i], fb[j], acc[i][j], 0, 0, 0);
  }
  #pragma unroll
  for (int i = 0; i < 2; ++i) {
    int rbase = r0 + wave * 32 + i * 16 + q * 4;
    #pragma unroll
    for (int j = 0; j < 3; ++j) {
      int col = j * 16 + mn;
      #pragma unroll
      for (int rr = 0; rr < 4; ++rr) {
        int row = rbase + rr;
        if (row < NN && col < NC) C[(size_t)row * NC + col] += acc[i][j][rr];
      }
    }
  }
}

// ---------------- SPMM fused: out = relu(agg + b) + res ----------------
// One WAVE per row; lane covers features {2*lane, 2*lane+1} (packed uint).
__global__ __launch_bounds__(256) void spmm_layer(
    const unsigned short* __restrict__ support, const int* __restrict__ cnt,
    const int2* __restrict__ ell, const unsigned short* __restrict__ bias,
    const unsigned short* __restrict__ res,
    unsigned short* __restrict__ out) {
  int wave = threadIdx.x >> 6, lane = threadIdx.x & 63;
  int row = blockIdx.x * 4 + wave;
  if (row >= NN) return;
  int n = cnt[row];
  if (n > CAP) n = CAP;
  int2 ev = make_int2(0, 0);
  if (lane < n) ev = ell[(size_t)row * CAP + lane];  // lane j holds edge j
  float a0 = 0.f, a1 = 0.f;
  int j = 0;
  for (; j + 8 <= n; j += 8) {
    uint32_t g[8];
    int sidx[8];
    #pragma unroll
    for (int u = 0; u < 8; ++u) sidx[u] = __shfl(ev.x, j + u);
    #pragma unroll
    for (int u = 0; u < 8; ++u)
      g[u] = *(const uint32_t*)(support + (size_t)sidx[u] * DH + 2 * lane);
    #pragma unroll
    for (int u = 0; u < 8; ++u) {
      union { int i; float f; } wv; wv.i = __shfl(ev.y, j + u);
      a0 += wv.f * bf2f((unsigned short)(g[u] & 0xffff));
      a1 += wv.f * bf2f((unsigned short)(g[u] >> 16));
    }
  }
  for (; j < n; ++j) {
    int s = __shfl(ev.x, j);
    union { int i; float f; } wv; wv.i = __shfl(ev.y, j);
    uint32_t g = *(const uint32_t*)(support + (size_t)s * DH + 2 * lane);
    a0 += wv.f * bf2f((unsigned short)(g & 0xffff));
    a1 += wv.f * bf2f((unsigned short)(g >> 16));
  }
  uint32_t bw = *(const uint32_t*)(bias + 2 * lane);
  uint32_t rw = *(const uint32_t*)(res + (size_t)row * DH + 2 * lane);
  float v0 = fmaxf(a0 + bf2f((unsigned short)(bw & 0xffff)), 0.f) +
             bf2f((unsigned short)(rw & 0xffff));
  float v1 = fmaxf(a1 + bf2f((unsigned short)(bw >> 16)), 0.f) +
             bf2f((unsigned short)(rw >> 16));
  uint32_t o = (uint32_t)f2bf(v0) | ((uint32_t)f2bf(v1) << 16);
  *(uint32_t*)(out + (size_t)row * DH + 2 * lane) = o;
}

// ---------------- final SPMM (d=40) + bias + log_softmax -> FP32 output ----------------
__global__ __launch_bounds__(256) void spmm_softmax_out(
    const float* __restrict__ s15, const int* __restrict__ cnt,
    const int2* __restrict__ ell, const unsigned short* __restrict__ bias,
    float* __restrict__ out) {
  int wave = threadIdx.x >> 6, lane = threadIdx.x & 63;
  int row = blockIdx.x * 4 + wave;
  if (row >= NN) return;
  int n = cnt[row];
  if (n > CAP) n = CAP;
  int2 ev = make_int2(0, 0);
  if (lane < n) ev = ell[(size_t)row * CAP + lane];
  int fl = lane < NC ? lane : NC - 1;  // keep all 64 lanes convergent for shfl
  float acc = 0.f;
  int j = 0;
  for (; j + 4 <= n; j += 4) {
    float g[4];
    #pragma unroll
    for (int u = 0; u < 4; ++u) {
      int s = __shfl(ev.x, j + u);
      g[u] = s15[(size_t)s * NC + fl];
    }
    #pragma unroll
    for (int u = 0; u < 4; ++u) {
      union { int i; float f; } wv; wv.i = __shfl(ev.y, j + u);
      acc += wv.f * g[u];
    }
  }
  for (; j < n; ++j) {
    int s = __shfl(ev.x, j);
    union { int i; float f; } wv; wv.i = __shfl(ev.y, j);
    acc += wv.f * s15[(size_t)s * NC + fl];
  }
  acc += bf2f(bias[fl]);
  float v = (lane < NC) ? acc : -3.0e38f;
  float m = v;
  #pragma unroll
  for (int off = 32; off > 0; off >>= 1) m = fmaxf(m, __shfl_xor(m, off));
  float e = (lane < NC) ? expf(v - m) : 0.f;
  float sum = e;
  #pragma unroll
  for (int off = 32; off > 0; off >>= 1) sum += __shfl_xor(sum, off);
  if (lane < NC) out[(size_t)row * NC + lane] = v - m - logf(sum);
}

extern "C" void kernel_launch(void* const* d_in, const int* in_sizes, int n_in,
                              void* d_out, int out_size, void* d_ws, size_t ws_size,
                              hipStream_t stream) {
  const void* x   = d_in[0];
  const int* esrc = (const int*)d_in[1];
  const int* edst = (const int*)d_in[2];
  const void* ew  = d_in[3];
  const void* W0  = d_in[4];
  const void* b0  = d_in[5];
  const void* W1  = d_in[6];
  const void* b1  = d_in[7];
  const void* Wm  = d_in[8];
  const void* bm  = d_in[9];
  const void* W15 = d_in[10];
  const void* b15 = d_in[11];
  float* out = (float*)d_out;   // reference output dtype = float32

  char* ws = (char*)d_ws;
  size_t off = 0;
  auto alloc = [&](size_t bytes) -> void* {
    void* p = ws + off;
    off = (off + bytes + 255) & ~(size_t)255;
    return p;
  };
  unsigned short* xls  = (unsigned short*)alloc((size_t)14 * NN * DH * 2);  // x1..x14, contiguous each
  unsigned short* xbf  = (unsigned short*)alloc((size_t)NN * 256 * 2);
  unsigned short* supp = (unsigned short*)alloc((size_t)NN * DH * 2);
  unsigned short* zbuf = (unsigned short*)alloc((size_t)NN * DH * 2);
  float* s15           = (float*)alloc((size_t)NN * NC * 4);
  int* counts          = (int*)alloc((size_t)(NN + 1) * 4);  // [NN] = dtype wild count
  int2* ell            = (int2*)alloc((size_t)NN * CAP * 8);
  unsigned short* W0T  = (unsigned short*)alloc((size_t)256 * 128 * 2);
  unsigned short* W1T  = (unsigned short*)alloc((size_t)256 * 128 * 2);
  unsigned short* WmT  = (unsigned short*)alloc((size_t)13 * 128 * 128 * 2);
  unsigned short* W15T = (unsigned short*)alloc((size_t)48 * 1792 * 2);
  unsigned short* bb   = (unsigned short*)alloc((size_t)(128 + 128 + 13 * 128 + 40) * 2);
  if (off > ws_size) return;  // signature: output stays zero
  int* flag = counts + NN;
  unsigned short* b0b  = bb;
  unsigned short* b1b  = bb + 128;
  unsigned short* bmb  = bb + 256;
  unsigned short* b15b = bb + 256 + 13 * 128;
  auto xl = [&](int l) { return xls + (size_t)(l - 1) * NN * DH; };  // l = 1..14

  zero_i32<<<197, 256, 0, stream>>>(counts, NN + 1);
  zero_i32<<<7813, 256, 0, stream>>>((int*)s15, NN * NC);  // gemm_acc accumulates into s15
  detect_dtype<<<1, 256, 0, stream>>>((const unsigned short*)x, flag);
  transpose_w<<<128, 256, 0, stream>>>(W0, W0T, 1, 256, 128, 128, flag);
  transpose_w<<<128, 256, 0, stream>>>(W1, W1T, 1, 256, 128, 128, flag);
  transpose_w<<<832, 256, 0, stream>>>(Wm, WmT, 13, 128, 128, 128, flag);
  transpose_w<<<336, 256, 0, stream>>>(W15, W15T, 1, 1792, 40, 48, flag);
  convert_f<<<2048, 256, 0, stream>>>(x, xbf, NN * 256, flag);
  convert_f<<<1, 128, 0, stream>>>(b0, b0b, 128, flag);
  convert_f<<<1, 128, 0, stream>>>(b1, b1b, 128, flag);
  convert_f<<<7, 256, 0, stream>>>(bm, bmb, 13 * 128, flag);
  convert_f<<<1, 64, 0, stream>>>(b15, b15b, 40, flag);
  build_ell<<<3125, 256, 0, stream>>>(esrc, edst, ew, counts, ell, flag);

  int gb = (NN + 63) / 64;     // 782
  int ab = (NN + 127) / 128;   // 391
  int sb = (NN + 3) / 4;       // 12500
  gemm_h<<<gb, 256, 0, stream>>>(xbf, 256, W0T, 256, 256, zbuf, b0b);      // z = x@W0+b0
  gemm_h<<<gb, 256, 0, stream>>>(xbf, 256, W1T, 256, 256, supp, nullptr);  // supp = x@W1
  spmm_layer<<<sb, 256, 0, stream>>>(supp, counts, ell, b1b, zbuf, xl(1)); // x1
  gemm_acc<<<ab, 256, 0, stream>>>(xl(1), W15T + 13 * 128, KCAT, s15);     // s15 += x1@W15[13]
  for (int l = 1; l <= 13; ++l) {
    gemm_h<<<gb, 256, 0, stream>>>(xl(l), 128, WmT + (l - 1) * 128 * 128, 128, 128,
                                   supp, nullptr);
    spmm_layer<<<sb, 256, 0, stream>>>(supp, counts, ell, bmb + (l - 1) * DH,
                                       xl(l), xl(l + 1));
    gemm_acc<<<ab, 256, 0, stream>>>(xl(l + 1), W15T + (13 - l) * 128, KCAT, s15);
  }
  spmm_softmax_out<<<sb, 256, 0, stream>>>(s15, counts, ell, b15b, out);
}

// Round 9
// 1181.389 us; speedup vs baseline: 1.0046x; 1.0046x over previous
//
#include <hip/hip_runtime.h>
#include <stdint.h>

#define NN 50000
#define EE 800000
#define DH 128
#define NC 40
#define CAP 64         // ELL capacity; deg ~ Poisson(16), P(deg>64) ~ e^-45
#define LP 72          // LDS row pad (shorts)

typedef __bf16 bf16x8 __attribute__((ext_vector_type(8)));
typedef float floatx4 __attribute__((ext_vector_type(4)));

__device__ __forceinline__ float bf2f(unsigned short u) {
  union { uint32_t i; float f; } v; v.i = ((uint32_t)u) << 16; return v.f;
}
__device__ __forceinline__ unsigned short f2bf(float f) {
  union { float f; uint32_t i; } v; v.f = f;
  uint32_t x = v.i;
  uint32_t r = (x + 0x7fffu + ((x >> 16) & 1u)) >> 16;  // RNE
  return (unsigned short)r;
}

// ---------------- utility ----------------
__global__ void zero_i32(int* p, int n) {
  int i = blockIdx.x * blockDim.x + threadIdx.x;
  if (i < n) p[i] = 0;
}

// Probe x's first 4096 16-bit words (R3: confirmed fp32 inputs; keep dtype-agnostic).
__global__ void detect_dtype(const unsigned short* xw, int* wildcnt) {
  int t = threadIdx.x;
  int wild = 0;
  for (int i = t; i < 4096; i += 256) {
    unsigned e = (xw[i] >> 7) & 0xFF;
    if (e >= 0x90) wild++;
  }
  if (wild) atomicAdd(wildcnt, wild);
}

__global__ void convert_f(const void* in, unsigned short* outp, int n, const int* flag) {
  bool isf32 = (*flag) > 32;
  for (int i = blockIdx.x * blockDim.x + threadIdx.x; i < n;
       i += gridDim.x * blockDim.x) {
    outp[i] = isf32 ? f2bf(((const float*)in)[i]) : ((const unsigned short*)in)[i];
  }
}

// B[L][K][M] -> BT[L][Mpad][K] (bf16 out), zero-pad n>=M
__global__ void transpose_w(const void* B, unsigned short* BT,
                            int L, int K, int M, int Mpad, const int* flag) {
  bool isf32 = (*flag) > 32;
  int total = L * Mpad * K;
  for (int idx = blockIdx.x * blockDim.x + threadIdx.x; idx < total;
       idx += gridDim.x * blockDim.x) {
    int k = idx % K;
    int n = (idx / K) % Mpad;
    int l = idx / (K * Mpad);
    unsigned short v = 0;
    if (n < M) {
      size_t si = (size_t)l * K * M + (size_t)k * M + n;
      v = isf32 ? f2bf(((const float*)B)[si]) : ((const unsigned short*)B)[si];
    }
    BT[idx] = v;
  }
}

// ---------------- ELL adjacency build ----------------
__global__ void build_ell(const int* __restrict__ src, const int* __restrict__ dst,
                          const void* __restrict__ w,
                          int* __restrict__ cnt, int2* __restrict__ ell,
                          const int* __restrict__ flag) {
  bool isf32 = (*flag) > 32;
  int e = blockIdx.x * blockDim.x + threadIdx.x;
  if (e >= EE) return;
  int d = dst[e];
  if ((unsigned)d >= NN) return;
  int p = atomicAdd(&cnt[d], 1);
  if (p >= CAP) return;
  int s = src[e];
  float wf = isf32 ? ((const float*)w)[e] : bf2f(((const unsigned short*)w)[e]);
  if ((unsigned)s >= NN) { s = 0; wf = 0.f; }
  union { float f; int i; } wv; wv.f = wf;
  ell[(size_t)d * CAP + p] = make_int2(s, wv.i);
}

// ---------------- GEMM: C[N,128] = A[N,K] @ B[K,128] (+bias) ----------------
// A contiguous (lda=K), BT [128][K]. 64x128 tile, BK=64, register prefetch of
// chunk c+1 issued BEFORE MFMA of chunk c (loads in flight across compute).
template<int K>
__global__ __launch_bounds__(256, 5) void gemm_h(
    const unsigned short* __restrict__ A,
    const unsigned short* __restrict__ BT,
    unsigned short* __restrict__ C, const unsigned short* __restrict__ bias) {
  __shared__ unsigned short As[64][LP];
  __shared__ unsigned short Bs[128][LP];
  int t = threadIdx.x;
  int wave = t >> 6, lane = t & 63;
  int q = lane >> 4, mn = lane & 15;
  int r0 = blockIdx.x * 64;
  floatx4 acc[8];
  floatx4 zf = {0.f, 0.f, 0.f, 0.f};
  #pragma unroll
  for (int j = 0; j < 8; ++j) acc[j] = zf;

  int arow = t >> 2;            // 0..63
  int akc = (t & 3) << 4;       // 0,16,32,48 shorts (32B/thread)
  int brow = t >> 1;            // 0..127
  int bkc = (t & 1) << 5;       // 0,32 shorts (64B/thread)
  bool aval = (r0 + arow) < NN;
  const unsigned short* aptr = A + (size_t)(r0 + arow) * K + akc;
  const unsigned short* bptr = BT + (size_t)brow * K + bkc;

  uint4 ar[2], br[4];
  auto ld = [&](int k0) {
    uint4 z = make_uint4(0, 0, 0, 0);
    ar[0] = aval ? *(const uint4*)(aptr + k0) : z;
    ar[1] = aval ? *(const uint4*)(aptr + k0 + 8) : z;
    #pragma unroll
    for (int i = 0; i < 4; ++i) br[i] = *(const uint4*)(bptr + k0 + i * 8);
  };
  ld(0);
  constexpr int NCH = K / 64;
  #pragma unroll
  for (int c = 0; c < NCH; ++c) {
    *(uint4*)(&As[arow][akc]) = ar[0];
    *(uint4*)(&As[arow][akc + 8]) = ar[1];
    #pragma unroll
    for (int i = 0; i < 4; ++i) *(uint4*)(&Bs[brow][bkc + i * 8]) = br[i];
    __syncthreads();
    if (c + 1 < NCH) ld((c + 1) * 64);   // prefetch next chunk into regs
    #pragma unroll
    for (int ks = 0; ks < 2; ++ks) {
      bf16x8 fa = *(const bf16x8*)(&As[wave * 16 + mn][ks * 32 + q * 8]);
      #pragma unroll
      for (int j = 0; j < 8; ++j) {
        bf16x8 fb = *(const bf16x8*)(&Bs[j * 16 + mn][ks * 32 + q * 8]);
        acc[j] = __builtin_amdgcn_mfma_f32_16x16x32_bf16(fa, fb, acc[j], 0, 0, 0);
      }
    }
    __syncthreads();
  }
  // epilogue: acc -> LDS (flat 64x128 in Bs) -> coalesced stores
  unsigned short* Es = &Bs[0][0];
  #pragma unroll
  for (int j = 0; j < 8; ++j) {
    int col = j * 16 + mn;
    float badd = bias ? bf2f(bias[col]) : 0.0f;
    #pragma unroll
    for (int rr = 0; rr < 4; ++rr)
      Es[(wave * 16 + q * 4 + rr) * 128 + col] = f2bf(acc[j][rr] + badd);
  }
  __syncthreads();
  if (aval) {
    int ec = (t & 3) << 5;  // 0,32,64,96 shorts; 32 shorts (64B) per thread
    unsigned short* dst = C + (size_t)(r0 + arow) * 128 + ec;
    #pragma unroll
    for (int i = 0; i < 4; ++i)
      *(uint4*)(dst + i * 8) = *(const uint4*)(Es + arow * 128 + ec + i * 8);
  }
}

// ---------------- final GEMM: s15[N,40] = sum_l x_l @ W15_blk (register acc, 1 pass) ----
// xls = 14 contiguous [NN][128] buffers; W15P = [14][48][128].
__global__ __launch_bounds__(256, 5) void gemm_cat14(
    const unsigned short* __restrict__ xls,
    const unsigned short* __restrict__ W15P,
    float* __restrict__ C) {
  __shared__ unsigned short As[128][LP];
  __shared__ unsigned short Bs[48][LP];
  int t = threadIdx.x;
  int wave = t >> 6, lane = t & 63;
  int q = lane >> 4, mn = lane & 15;
  int r0 = blockIdx.x * 128;
  floatx4 acc[2][3];
  floatx4 zf = {0.f, 0.f, 0.f, 0.f};
  #pragma unroll
  for (int i = 0; i < 2; ++i)
    #pragma unroll
    for (int j = 0; j < 3; ++j) acc[i][j] = zf;

  int arow = t >> 1;            // 0..127
  int akc = (t & 1) << 5;       // 0,32 shorts (64B/thread)
  int brw = t >> 2;             // 0..63 (use <48)
  int bkc = (t & 3) << 4;       // 0,16,32,48 shorts (32B/thread)
  bool aval = (r0 + arow) < NN;

  uint4 ar[4], br[2];
  auto ld = [&](int bl, int h) {
    const unsigned short* ap =
        xls + (size_t)(13 - bl) * NN * DH + (size_t)(r0 + arow) * DH + h * 64 + akc;
    uint4 z = make_uint4(0, 0, 0, 0);
    #pragma unroll
    for (int i = 0; i < 4; ++i) ar[i] = aval ? *(const uint4*)(ap + i * 8) : z;
    if (brw < 48) {
      const unsigned short* bp =
          W15P + (size_t)bl * 48 * 128 + (size_t)brw * 128 + h * 64 + bkc;
      br[0] = *(const uint4*)(bp);
      br[1] = *(const uint4*)(bp + 8);
    }
  };
  ld(0, 0);
  for (int ch = 0; ch < 28; ++ch) {
    #pragma unroll
    for (int i = 0; i < 4; ++i) *(uint4*)(&As[arow][akc + i * 8]) = ar[i];
    if (brw < 48) {
      *(uint4*)(&Bs[brw][bkc]) = br[0];
      *(uint4*)(&Bs[brw][bkc + 8]) = br[1];
    }
    __syncthreads();
    if (ch + 1 < 28) ld((ch + 1) >> 1, (ch + 1) & 1);
    #pragma unroll
    for (int ks = 0; ks < 2; ++ks) {
      bf16x8 fa[2], fb[3];
      #pragma unroll
      for (int i = 0; i < 2; ++i)
        fa[i] = *(const bf16x8*)(&As[wave * 32 + i * 16 + mn][ks * 32 + q * 8]);
      #pragma unroll
      for (int j = 0; j < 3; ++j)
        fb[j] = *(const bf16x8*)(&Bs[j * 16 + mn][ks * 32 + q * 8]);
      #pragma unroll
      for (int i = 0; i < 2; ++i)
        #pragma unroll
        for (int j = 0; j < 3; ++j)
          acc[i][j] = __builtin_amdgcn_mfma_f32_16x16x32_bf16(fa[i], fb[j], acc[i][j], 0, 0, 0);
    }
    __syncthreads();
  }
  #pragma unroll
  for (int i = 0; i < 2; ++i) {
    int rbase = r0 + wave * 32 + i * 16 + q * 4;
    #pragma unroll
    for (int j = 0; j < 3; ++j) {
      int col = j * 16 + mn;
      #pragma unroll
      for (int rr = 0; rr < 4; ++rr) {
        int row = rbase + rr;
        if (row < NN && col < NC) C[(size_t)row * NC + col] = acc[i][j][rr];
      }
    }
  }
}

// ---------------- SPMM fused: out = relu(agg + b) + res ----------------
__global__ __launch_bounds__(256) void spmm_layer(
    const unsigned short* __restrict__ support, const int* __restrict__ cnt,
    const int2* __restrict__ ell, const unsigned short* __restrict__ bias,
    const unsigned short* __restrict__ res,
    unsigned short* __restrict__ out) {
  int wave = threadIdx.x >> 6, lane = threadIdx.x & 63;
  int row = blockIdx.x * 4 + wave;
  if (row >= NN) return;
  int n = cnt[row];
  if (n > CAP) n = CAP;
  int2 ev = make_int2(0, 0);
  if (lane < n) ev = ell[(size_t)row * CAP + lane];
  float a0 = 0.f, a1 = 0.f;
  int j = 0;
  for (; j + 8 <= n; j += 8) {
    uint32_t g[8];
    int sidx[8];
    #pragma unroll
    for (int u = 0; u < 8; ++u) sidx[u] = __shfl(ev.x, j + u);
    #pragma unroll
    for (int u = 0; u < 8; ++u)
      g[u] = *(const uint32_t*)(support + (size_t)sidx[u] * DH + 2 * lane);
    #pragma unroll
    for (int u = 0; u < 8; ++u) {
      union { int i; float f; } wv; wv.i = __shfl(ev.y, j + u);
      a0 += wv.f * bf2f((unsigned short)(g[u] & 0xffff));
      a1 += wv.f * bf2f((unsigned short)(g[u] >> 16));
    }
  }
  for (; j < n; ++j) {
    int s = __shfl(ev.x, j);
    union { int i; float f; } wv; wv.i = __shfl(ev.y, j);
    uint32_t g = *(const uint32_t*)(support + (size_t)s * DH + 2 * lane);
    a0 += wv.f * bf2f((unsigned short)(g & 0xffff));
    a1 += wv.f * bf2f((unsigned short)(g >> 16));
  }
  uint32_t bw = *(const uint32_t*)(bias + 2 * lane);
  uint32_t rw = *(const uint32_t*)(res + (size_t)row * DH + 2 * lane);
  float v0 = fmaxf(a0 + bf2f((unsigned short)(bw & 0xffff)), 0.f) +
             bf2f((unsigned short)(rw & 0xffff));
  float v1 = fmaxf(a1 + bf2f((unsigned short)(bw >> 16)), 0.f) +
             bf2f((unsigned short)(rw >> 16));
  uint32_t o = (uint32_t)f2bf(v0) | ((uint32_t)f2bf(v1) << 16);
  *(uint32_t*)(out + (size_t)row * DH + 2 * lane) = o;
}

// ---------------- final SPMM (d=40) + bias + log_softmax -> FP32 output ----------------
__global__ __launch_bounds__(256) void spmm_softmax_out(
    const float* __restrict__ s15, const int* __restrict__ cnt,
    const int2* __restrict__ ell, const unsigned short* __restrict__ bias,
    float* __restrict__ out) {
  int wave = threadIdx.x >> 6, lane = threadIdx.x & 63;
  int row = blockIdx.x * 4 + wave;
  if (row >= NN) return;
  int n = cnt[row];
  if (n > CAP) n = CAP;
  int2 ev = make_int2(0, 0);
  if (lane < n) ev = ell[(size_t)row * CAP + lane];
  int fl = lane < NC ? lane : NC - 1;
  float acc = 0.f;
  int j = 0;
  for (; j + 4 <= n; j += 4) {
    float g[4];
    #pragma unroll
    for (int u = 0; u < 4; ++u) {
      int s = __shfl(ev.x, j + u);
      g[u] = s15[(size_t)s * NC + fl];
    }
    #pragma unroll
    for (int u = 0; u < 4; ++u) {
      union { int i; float f; } wv; wv.i = __shfl(ev.y, j + u);
      acc += wv.f * g[u];
    }
  }
  for (; j < n; ++j) {
    int s = __shfl(ev.x, j);
    union { int i; float f; } wv; wv.i = __shfl(ev.y, j);
    acc += wv.f * s15[(size_t)s * NC + fl];
  }
  acc += bf2f(bias[fl]);
  float v = (lane < NC) ? acc : -3.0e38f;
  float m = v;
  #pragma unroll
  for (int off = 32; off > 0; off >>= 1) m = fmaxf(m, __shfl_xor(m, off));
  float e = (lane < NC) ? expf(v - m) : 0.f;
  float sum = e;
  #pragma unroll
  for (int off = 32; off > 0; off >>= 1) sum += __shfl_xor(sum, off);
  if (lane < NC) out[(size_t)row * NC + lane] = v - m - logf(sum);
}

extern "C" void kernel_launch(void* const* d_in, const int* in_sizes, int n_in,
                              void* d_out, int out_size, void* d_ws, size_t ws_size,
                              hipStream_t stream) {
  const void* x   = d_in[0];
  const int* esrc = (const int*)d_in[1];
  const int* edst = (const int*)d_in[2];
  const void* ew  = d_in[3];
  const void* W0  = d_in[4];
  const void* b0  = d_in[5];
  const void* W1  = d_in[6];
  const void* b1  = d_in[7];
  const void* Wm  = d_in[8];
  const void* bm  = d_in[9];
  const void* W15 = d_in[10];
  const void* b15 = d_in[11];
  float* out = (float*)d_out;

  char* ws = (char*)d_ws;
  size_t off = 0;
  auto alloc = [&](size_t bytes) -> void* {
    void* p = ws + off;
    off = (off + bytes + 255) & ~(size_t)255;
    return p;
  };
  unsigned short* xls  = (unsigned short*)alloc((size_t)14 * NN * DH * 2);  // x1..x14
  unsigned short* xbf  = (unsigned short*)alloc((size_t)NN * 256 * 2);
  unsigned short* supp = (unsigned short*)alloc((size_t)NN * DH * 2);
  unsigned short* zbuf = (unsigned short*)alloc((size_t)NN * DH * 2);
  float* s15           = (float*)alloc((size_t)NN * NC * 4);
  int* counts          = (int*)alloc((size_t)(NN + 1) * 4);
  int2* ell            = (int2*)alloc((size_t)NN * CAP * 8);
  unsigned short* W0T  = (unsigned short*)alloc((size_t)128 * 256 * 2);
  unsigned short* W1T  = (unsigned short*)alloc((size_t)128 * 256 * 2);
  unsigned short* WmT  = (unsigned short*)alloc((size_t)13 * 128 * 128 * 2);
  unsigned short* W15P = (unsigned short*)alloc((size_t)14 * 48 * 128 * 2);
  unsigned short* bb   = (unsigned short*)alloc((size_t)(128 + 128 + 13 * 128 + 40) * 2);
  if (off > ws_size) return;
  int* flag = counts + NN;
  unsigned short* b0b  = bb;
  unsigned short* b1b  = bb + 128;
  unsigned short* bmb  = bb + 256;
  unsigned short* b15b = bb + 256 + 13 * 128;
  auto xl = [&](int l) { return xls + (size_t)(l - 1) * NN * DH; };  // l = 1..14

  zero_i32<<<197, 256, 0, stream>>>(counts, NN + 1);
  detect_dtype<<<1, 256, 0, stream>>>((const unsigned short*)x, flag);
  transpose_w<<<128, 256, 0, stream>>>(W0, W0T, 1, 256, 128, 128, flag);
  transpose_w<<<128, 256, 0, stream>>>(W1, W1T, 1, 256, 128, 128, flag);
  transpose_w<<<832, 256, 0, stream>>>(Wm, WmT, 13, 128, 128, 128, flag);
  transpose_w<<<336, 256, 0, stream>>>(W15, W15P, 14, 128, 40, 48, flag);
  convert_f<<<2048, 256, 0, stream>>>(x, xbf, NN * 256, flag);
  convert_f<<<1, 128, 0, stream>>>(b0, b0b, 128, flag);
  convert_f<<<1, 128, 0, stream>>>(b1, b1b, 128, flag);
  convert_f<<<7, 256, 0, stream>>>(bm, bmb, 13 * 128, flag);
  convert_f<<<1, 64, 0, stream>>>(b15, b15b, 40, flag);
  build_ell<<<3125, 256, 0, stream>>>(esrc, edst, ew, counts, ell, flag);

  int gb = (NN + 63) / 64;     // 782
  int ab = (NN + 127) / 128;   // 391
  int sb = (NN + 3) / 4;       // 12500
  gemm_h<256><<<gb, 256, 0, stream>>>(xbf, W0T, zbuf, b0b);      // z = x@W0+b0
  gemm_h<256><<<gb, 256, 0, stream>>>(xbf, W1T, supp, nullptr);  // supp = x@W1
  spmm_layer<<<sb, 256, 0, stream>>>(supp, counts, ell, b1b, zbuf, xl(1));
  for (int l = 1; l <= 13; ++l) {
    gemm_h<128><<<gb, 256, 0, stream>>>(xl(l), WmT + (l - 1) * 128 * 128, supp, nullptr);
    spmm_layer<<<sb, 256, 0, stream>>>(supp, counts, ell, bmb + (l - 1) * DH,
                                       xl(l), xl(l + 1));
  }
  gemm_cat14<<<ab, 256, 0, stream>>>(xls, W15P, s15);
  spmm_softmax_out<<<sb, 256, 0, stream>>>(s15, counts, ell, b15b, out);
}